// Round 1
// baseline (573.517 us; speedup 1.0000x reference)
//
#include <hip/hip_runtime.h>

typedef __attribute__((ext_vector_type(8))) short s8v;
typedef __attribute__((ext_vector_type(4))) short s4v;
typedef __attribute__((ext_vector_type(4))) float f4v;

constexpr int SEQ = 2048;
constexpr int EMB = 512;
constexpr int BATCH = 8;
constexpr int BS = BATCH * SEQ;  // 16384

#define DEVINL __device__ __forceinline__

DEVINL float bf2f(short s) {
    union { unsigned u; float f; } v;
    v.u = ((unsigned)(unsigned short)s) << 16;
    return v.f;
}
DEVINL short f2bf(float f) {
    union { float f; unsigned u; } v; v.f = f;
    unsigned u = v.u;
    return (short)((u + 0x7FFFu + ((u >> 16) & 1u)) >> 16);
}
DEVINL float sigmf(float x) {
    return __builtin_amdgcn_rcpf(1.0f + __expf(-x));
}
DEVINL f4v mfma16(s8v a, s8v b, f4v c) {
    return __builtin_amdgcn_mfma_f32_16x16x32_bf16(a, b, c, 0, 0, 0);
}
DEVINL s8v pack8(float4 a, float4 b) {
    s8v o;
    o[0] = f2bf(a.x); o[1] = f2bf(a.y); o[2] = f2bf(a.z); o[3] = f2bf(a.w);
    o[4] = f2bf(b.x); o[5] = f2bf(b.y); o[6] = f2bf(b.z); o[7] = f2bf(b.w);
    return o;
}

// ---------------- prep kernels ----------------

// normalize each row of trajectories (E=512) and cast to bf16
__global__ __launch_bounds__(256) void prep_tn(const float* __restrict__ x,
                                               short* __restrict__ y) {
    int row = blockIdx.x * 4 + (threadIdx.x >> 6);
    int lane = threadIdx.x & 63;
    const float* p = x + (size_t)row * EMB + lane * 8;
    float4 a = *(const float4*)p;
    float4 b = *(const float4*)(p + 4);
    float ss = a.x*a.x + a.y*a.y + a.z*a.z + a.w*a.w
             + b.x*b.x + b.y*b.y + b.z*b.z + b.w*b.w;
#pragma unroll
    for (int m = 32; m >= 1; m >>= 1) ss += __shfl_xor(ss, m);
    float inv = __builtin_amdgcn_rcpf(fmaxf(sqrtf(ss), 1e-12f));
    float4 sa = make_float4(a.x*inv, a.y*inv, a.z*inv, a.w*inv);
    float4 sb = make_float4(b.x*inv, b.y*inv, b.z*inv, b.w*inv);
    *(s8v*)(y + (size_t)row * EMB + lane * 8) = pack8(sa, sb);
}

__global__ __launch_bounds__(256) void cast8(const float* __restrict__ x,
                                             short* __restrict__ y, int n8) {
    int i = blockIdx.x * 256 + threadIdx.x;
    if (i >= n8) return;
    const float* p = x + (size_t)i * 8;
    float4 a = *(const float4*)p;
    float4 b = *(const float4*)(p + 4);
    *(s8v*)(y + (size_t)i * 8) = pack8(a, b);
}

// W [512k][512n] f32 -> WT [n][k] bf16
__global__ __launch_bounds__(256) void castWT(const float* __restrict__ W,
                                              short* __restrict__ WT) {
    int t = blockIdx.x * 256 + threadIdx.x;  // 32768 threads
    int n = t >> 6;
    int k0 = (t & 63) * 8;
    s8v o;
#pragma unroll
    for (int e = 0; e < 8; e++) o[e] = f2bf(W[(size_t)(k0 + e) * EMB + n]);
    *(s8v*)(WT + (size_t)n * EMB + k0) = o;
}

// ---------------- generic 512-col GEMM with fused epilogues ----------------
// C[BS x 512] = A_bf16[BS x 512] @ WT^T + bias, block = 32 rows, 4 waves x 128 cols
// EPI 0: store bf16 transposed per batch (Vt[b][e][s])
// EPI 1: relu, store bf16 row-major
// EPI 2: + resid, LayerNorm -> outf f32 + outb bf16
// EPI 3: + resid, LayerNorm -> outf f32 only
template <int EPI>
__global__ __launch_bounds__(256) void gemm512(
    const short* __restrict__ A, const short* __restrict__ WT,
    const float* __restrict__ bias, const float* __restrict__ resid,
    float* __restrict__ outf, short* __restrict__ outb,
    const float* __restrict__ gam, const float* __restrict__ bet) {
    __shared__ float lsum[32];
    __shared__ float lsq[32];
    const int tid = threadIdx.x;
    const int wave = tid >> 6, lane = tid & 63;
    const int lr = lane & 15, kg = lane >> 4;
    const int rowbase = blockIdx.x * 32;
    const int colbase = wave * 128;
    if constexpr (EPI >= 2) {
        if (tid < 32) { lsum[tid] = 0.f; lsq[tid] = 0.f; }
        __syncthreads();
    }
    f4v acc[2][8] = {};
    const short* Ap0 = A + (size_t)(rowbase + lr) * EMB + kg * 8;
    const short* Ap1 = Ap0 + 16 * EMB;
    const short* Bp  = WT + (size_t)(colbase + lr) * EMB + kg * 8;
    for (int kk = 0; kk < EMB; kk += 32) {
        s8v a0 = *(const s8v*)(Ap0 + kk);
        s8v a1 = *(const s8v*)(Ap1 + kk);
#pragma unroll
        for (int n = 0; n < 8; n++) {
            s8v bv = *(const s8v*)(Bp + (size_t)n * 16 * EMB + kk);
            acc[0][n] = mfma16(a0, bv, acc[0][n]);
            acc[1][n] = mfma16(a1, bv, acc[1][n]);
        }
    }
    float bcol[8];
#pragma unroll
    for (int n = 0; n < 8; n++) bcol[n] = bias[colbase + n * 16 + lr];

    if constexpr (EPI == 0) {
#pragma unroll
        for (int m = 0; m < 2; m++) {
            int grow0 = rowbase + m * 16 + kg * 4;
            int bb = grow0 >> 11;
            int s0 = grow0 & (SEQ - 1);
#pragma unroll
            for (int n = 0; n < 8; n++) {
                int col = colbase + n * 16 + lr;
                s4v o;
#pragma unroll
                for (int r = 0; r < 4; r++) o[r] = f2bf(acc[m][n][r] + bcol[n]);
                *(s4v*)(outb + ((size_t)(bb * EMB + col)) * SEQ + s0) = o;
            }
        }
    } else if constexpr (EPI == 1) {
#pragma unroll
        for (int m = 0; m < 2; m++)
#pragma unroll
            for (int n = 0; n < 8; n++) {
                int col = colbase + n * 16 + lr;
#pragma unroll
                for (int r = 0; r < 4; r++) {
                    int grow = rowbase + m * 16 + kg * 4 + r;
                    outb[(size_t)grow * EMB + col] =
                        f2bf(fmaxf(acc[m][n][r] + bcol[n], 0.f));
                }
            }
    } else {
        float sm[2][4] = {}, sq2[2][4] = {};
#pragma unroll
        for (int m = 0; m < 2; m++)
#pragma unroll
            for (int n = 0; n < 8; n++) {
                int col = colbase + n * 16 + lr;
#pragma unroll
                for (int r = 0; r < 4; r++) {
                    int grow = rowbase + m * 16 + kg * 4 + r;
                    float v = acc[m][n][r] + bcol[n] + resid[(size_t)grow * EMB + col];
                    acc[m][n][r] = v;
                    sm[m][r] += v;
                    sq2[m][r] += v * v;
                }
            }
#pragma unroll
        for (int m = 0; m < 2; m++)
#pragma unroll
            for (int r = 0; r < 4; r++) {
                float s = sm[m][r], t = sq2[m][r];
                s += __shfl_xor(s, 1); t += __shfl_xor(t, 1);
                s += __shfl_xor(s, 2); t += __shfl_xor(t, 2);
                s += __shfl_xor(s, 4); t += __shfl_xor(t, 4);
                s += __shfl_xor(s, 8); t += __shfl_xor(t, 8);
                if (lr == 0) {
                    atomicAdd(&lsum[m * 16 + kg * 4 + r], s);
                    atomicAdd(&lsq[m * 16 + kg * 4 + r], t);
                }
            }
        __syncthreads();
#pragma unroll
        for (int m = 0; m < 2; m++)
#pragma unroll
            for (int r = 0; r < 4; r++) {
                int rowl = m * 16 + kg * 4 + r;
                int grow = rowbase + rowl;
                float mean = lsum[rowl] * (1.f / EMB);
                float var = lsq[rowl] * (1.f / EMB) - mean * mean;
                float rstd = rsqrtf(var + 1e-5f);
#pragma unroll
                for (int n = 0; n < 8; n++) {
                    int col = colbase + n * 16 + lr;
                    float yv = (acc[m][n][r] - mean) * rstd * gam[col] + bet[col];
                    outf[(size_t)grow * EMB + col] = yv;
                    if constexpr (EPI == 2)
                        outb[(size_t)grow * EMB + col] = f2bf(yv);
                }
            }
    }
}

// ---------------- fused similarity-attention kernel ----------------
// Per block: 32 query rows of one batch.
// Pass A: c = TN_I @ TN^T (MFMA), s1 = exp(avg4sigmoid(c)) -> S1 (bf16, global),
//         Z1 row sums in LDS.
// Pass B: q_j = exp(s1_j / Z1) for j>i (1.0 everywhere for last row, 0 masked),
//         attended = (Q @ V) / Z2 using Vt[b][e][s], output ATT bf16 row-major.
__global__ __launch_bounds__(256) void attn_kernel(
    const short* __restrict__ TN, const short* __restrict__ Vt,
    short* __restrict__ S1, short* __restrict__ ATT) {
    __shared__ __attribute__((aligned(16))) short Abuf[32 * EMB];   // 32KB swizzled
    __shared__ __attribute__((aligned(16))) short Qbuf[32 * 128];   // 8KB swizzled
    __shared__ float z1[32];
    __shared__ float z2[32];

    int bid = blockIdx.x;
    int swz = (bid & 7) * 64 + (bid >> 3);  // batch -> XCD locality
    int b = swz >> 6;
    int ibase = (swz & 63) * 32;
    int tid = threadIdx.x;
    int wave = tid >> 6, lane = tid & 63, lr = lane & 15, kg = lane >> 4;

    const short* TNb = TN + (size_t)b * SEQ * EMB;
    const short* TNi = TNb + (size_t)ibase * EMB;

    // stage A tile (32 x 512) into LDS, XOR-swizzled by row
#pragma unroll
    for (int g = 0; g < 8; g++) {
        int idx = g * 256 + tid;
        int row = idx >> 6, c16 = idx & 63;
        int boff = ((row << 10) | (c16 << 4)) ^ ((row & 7) << 4);
        *(s8v*)((char*)Abuf + boff) = *(const s8v*)(TNi + (size_t)row * EMB + c16 * 8);
    }
    if (tid < 32) { z1[tid] = 0.f; z2[tid] = 0.f; }
    __syncthreads();

    short* S1b = S1 + ((size_t)b * SEQ + ibase) * SEQ;

    // ---- PASS A ----
    float z1p[2][4] = {};
    for (int jb = 0; jb < SEQ; jb += 512) {
        int jcol = jb + wave * 128;
        f4v acc[2][8] = {};
        for (int kk = 0; kk < EMB; kk += 32) {
            s8v a0, a1;
            {
                int row = lr;
                int boff = ((row << 10) | ((kk + kg * 8) << 1)) ^ ((row & 7) << 4);
                a0 = *(const s8v*)((char*)Abuf + boff);
            }
            {
                int row = 16 + lr;
                int boff = ((row << 10) | ((kk + kg * 8) << 1)) ^ ((row & 7) << 4);
                a1 = *(const s8v*)((char*)Abuf + boff);
            }
#pragma unroll
            for (int n = 0; n < 8; n++) {
                s8v bv = *(const s8v*)(TNb + (size_t)(jcol + n * 16 + lr) * EMB + kk + kg * 8);
                acc[0][n] = mfma16(a0, bv, acc[0][n]);
                acc[1][n] = mfma16(a1, bv, acc[1][n]);
            }
        }
#pragma unroll
        for (int m = 0; m < 2; m++)
#pragma unroll
            for (int n = 0; n < 8; n++)
#pragma unroll
                for (int r = 0; r < 4; r++) {
                    float c = acc[m][n][r];
                    float aw = 0.25f * (sigmf(c) + sigmf(c * c) +
                                        sigmf(__expf(c - 1.0f)) +
                                        sigmf(0.5f * c + 0.5f));
                    short eb = f2bf(__expf(aw));
                    S1b[(size_t)(m * 16 + kg * 4 + r) * SEQ + jcol + n * 16 + lr] = eb;
                    z1p[m][r] += bf2f(eb);
                }
    }
#pragma unroll
    for (int m = 0; m < 2; m++)
#pragma unroll
        for (int r = 0; r < 4; r++) {
            float s = z1p[m][r];
            s += __shfl_xor(s, 1);
            s += __shfl_xor(s, 2);
            s += __shfl_xor(s, 4);
            s += __shfl_xor(s, 8);
            if (lr == 0) atomicAdd(&z1[m * 16 + kg * 4 + r], s);
        }
    __syncthreads();  // Z1 final; S1 stores drained before barrier

    // ---- PASS B ----
    int qrow = tid >> 3;           // 0..31 (producer row)
    int qc0 = (tid & 7) * 16;      // producer col offset within 128
    int gi = ibase + qrow;
    bool lastrow = (gi == SEQ - 1);
    float invz1 = __builtin_amdgcn_rcpf(z1[qrow]);
    float myz2 = 0.f;
    f4v acc[2][8] = {};
    const short* Vtw = Vt + (size_t)b * EMB * SEQ + (size_t)(wave * 128 + lr) * SEQ;

    for (int jb = 0; jb < SEQ; jb += 128) {
        __syncthreads();  // protect Qbuf from previous readers
#pragma unroll
        for (int h = 0; h < 2; h++) {
            int jc = jb + qc0 + h * 8;
            s8v sv = *(const s8v*)(S1b + (size_t)qrow * SEQ + jc);
            s8v qv;
#pragma unroll
            for (int e = 0; e < 8; e++) {
                int j = jc + e;
                float qq;
                if (lastrow) qq = 1.0f;
                else if (j > gi) qq = __expf(bf2f(sv[e]) * invz1);
                else qq = 0.0f;
                short qb = f2bf(qq);
                qv[e] = qb;
                myz2 += bf2f(qb);  // sum rounded values for consistency with MFMA
            }
            int boff = ((qrow << 8) | ((qc0 + h * 8) << 1)) ^ ((qrow & 7) << 4);
            *(s8v*)((char*)Qbuf + boff) = qv;
        }
        __syncthreads();
#pragma unroll
        for (int ks = 0; ks < 4; ks++) {
            s8v a0, a1;
            {
                int row = lr;
                int boff = ((row << 8) | ((ks * 32 + kg * 8) << 1)) ^ ((row & 7) << 4);
                a0 = *(const s8v*)((char*)Qbuf + boff);
            }
            {
                int row = 16 + lr;
                int boff = ((row << 8) | ((ks * 32 + kg * 8) << 1)) ^ ((row & 7) << 4);
                a1 = *(const s8v*)((char*)Qbuf + boff);
            }
#pragma unroll
            for (int n = 0; n < 8; n++) {
                s8v bv = *(const s8v*)(Vtw + (size_t)n * 16 * SEQ + jb + ks * 32 + kg * 8);
                acc[0][n] = mfma16(a0, bv, acc[0][n]);
                acc[1][n] = mfma16(a1, bv, acc[1][n]);
            }
        }
    }
    atomicAdd(&z2[qrow], myz2);
    __syncthreads();

    short* ATTb = ATT + ((size_t)b * SEQ + ibase) * EMB;
#pragma unroll
    for (int m = 0; m < 2; m++)
#pragma unroll
        for (int r = 0; r < 4; r++) {
            int rowl = m * 16 + kg * 4 + r;
            float wsc = __builtin_amdgcn_rcpf(z2[rowl]);
#pragma unroll
            for (int n = 0; n < 8; n++)
                ATTb[(size_t)rowl * EMB + wave * 128 + n * 16 + lr] =
                    f2bf(acc[m][n][r] * wsc);
        }
}

// ---------------- launch ----------------

extern "C" void kernel_launch(void* const* d_in, const int* in_sizes, int n_in,
                              void* d_out, int out_size, void* d_ws, size_t ws_size,
                              hipStream_t stream) {
    (void)in_sizes; (void)n_in; (void)out_size; (void)ws_size;
    const float* q     = (const float*)d_in[0];
    const float* k     = (const float*)d_in[1];
    const float* traj  = (const float*)d_in[2];
    const float* v_W   = (const float*)d_in[3];
    const float* v_b   = (const float*)d_in[4];
    const float* out_W = (const float*)d_in[5];
    const float* out_b = (const float*)d_in[6];
    const float* ln1_g = (const float*)d_in[7];
    const float* ln1_b = (const float*)d_in[8];
    const float* w1    = (const float*)d_in[9];
    const float* b1    = (const float*)d_in[10];
    const float* w2    = (const float*)d_in[11];
    const float* b2    = (const float*)d_in[12];
    const float* ln2_g = (const float*)d_in[13];
    const float* ln2_b = (const float*)d_in[14];

    char* ws = (char*)d_ws;
    const size_t MB = 1u << 20;
    short* TN  = (short*)(ws);            // 16MB bf16 normalized trajectories
    short* KB  = (short*)(ws + 16 * MB);  // 16MB bf16 k  (dead after V-gemm)
    short* ATT = KB;                      // reuse region for attended (bf16)
    short* WvT = (short*)(ws + 32 * MB);  // 4 x 0.5MB transposed bf16 weights
    short* WoT = WvT + 512 * 512;
    short* W1T = WoT + 512 * 512;
    short* W2T = W1T + 512 * 512;
    short* Vt  = (short*)(ws + 34 * MB);  // 16MB bf16 V transposed [b][e][s]
    short* S1  = (short*)(ws + 50 * MB);  // 64MB bf16 exp(avgsig(c))  (dead after attn)
    float* X   = (float*)(ws + 50 * MB);  // 32MB f32 x (post-LN1), overlaps dead S1
    short* Xbf = (short*)(ws + 82 * MB);  // 16MB bf16 x
    short* H1  = (short*)(ws + 98 * MB);  // 16MB bf16 relu(x@w1+b1)   (ends 114MB)

    prep_tn<<<BS / 4, 256, 0, stream>>>(traj, TN);
    cast8<<<BS * EMB / 8 / 256, 256, 0, stream>>>(k, KB, BS * EMB / 8);
    castWT<<<128, 256, 0, stream>>>(v_W, WvT);
    castWT<<<128, 256, 0, stream>>>(out_W, WoT);
    castWT<<<128, 256, 0, stream>>>(w1, W1T);
    castWT<<<128, 256, 0, stream>>>(w2, W2T);

    // V = k @ v_W + v_b  -> Vt (transposed bf16)
    gemm512<0><<<BS / 32, 256, 0, stream>>>(KB, WvT, v_b, nullptr, nullptr, Vt,
                                            nullptr, nullptr);
    // similarity + double softmax + PV -> ATT
    attn_kernel<<<BS / 32, 256, 0, stream>>>(TN, Vt, S1, ATT);
    // attn_out = ATT @ out_W + out_b; x = LN1(q + attn_out) -> X, Xbf
    gemm512<2><<<BS / 32, 256, 0, stream>>>(ATT, WoT, out_b, q, X, Xbf, ln1_g,
                                            ln1_b);
    // h1 = relu(x @ w1 + b1) -> H1
    gemm512<1><<<BS / 32, 256, 0, stream>>>(Xbf, W1T, b1, nullptr, nullptr, H1,
                                            nullptr, nullptr);
    // out = LN2(x + h1 @ w2 + b2) -> d_out
    gemm512<3><<<BS / 32, 256, 0, stream>>>(H1, W2T, b2, X, (float*)d_out,
                                            nullptr, ln2_g, ln2_b);
}